// Round 14
// baseline (885.343 us; speedup 1.0000x reference)
//
#include <hip/hip_runtime.h>

typedef __attribute__((ext_vector_type(8))) short short8;
typedef __attribute__((ext_vector_type(4))) float f32x4;

__device__ __forceinline__ ushort f2bf(float f){
    union { float f; unsigned u; } v; v.f = f;
    unsigned r = (v.u + 0x7fffu + ((v.u >> 16) & 1u)) >> 16;
    return (ushort)r;
}
__device__ __forceinline__ float bf2f(ushort u){
    union { unsigned u; float f; } v; v.u = ((unsigned)u) << 16;
    return v.f;
}

// ---------------- Layer 1: Cin=1 -> 40 real (stored 64, pad zero), direct fp32 ----------
__global__ __launch_bounds__(256) void conv_l1(
    const float* __restrict__ x, const float* __restrict__ w,
    const float* __restrict__ bias, ushort* __restrict__ out)
{
    __shared__ float xs[2916];     // [3][3][18][18] padded neighborhood
    __shared__ float wsh[3240];    // [40][81]
    const int tid = threadIdx.x;
    const int bx = blockIdx.x;
    const int d2 = bx & 15, d1 = (bx >> 4) & 15, b = bx >> 8;
    const float* xb = x + (size_t)b * 65536;

    for (int i = tid; i < 2916; i += 256){
        int i4 = i % 18; int r1 = i / 18; int i3 = r1 % 18;
        int r2 = r1 / 18; int a2 = r2 % 3; int a1 = r2 / 3;
        int e1 = d1 + a1 - 1, e2 = d2 + a2 - 1, e3 = i3 - 1, e4 = i4 - 1;
        float v = 0.f;
        if ((unsigned)e1 < 16u && (unsigned)e2 < 16u && (unsigned)e3 < 16u && (unsigned)e4 < 16u)
            v = xb[((e1 * 16 + e2) * 16 + e3) * 16 + e4];
        xs[i] = v;
    }
    for (int i = tid; i < 3240; i += 256) wsh[i] = w[i];
    __syncthreads();

    const int d3 = tid >> 4, d4 = tid & 15;
    float acc[40];
    #pragma unroll
    for (int c = 0; c < 40; ++c) acc[c] = 0.f;

    for (int t1 = 0; t1 < 3; ++t1)
    for (int t2 = 0; t2 < 3; ++t2)
    for (int t3 = 0; t3 < 3; ++t3)
    #pragma unroll
    for (int t4 = 0; t4 < 3; ++t4){
        float xv = xs[((t1 * 3 + t2) * 18 + d3 + t3) * 18 + d4 + t4];
        int tap = ((t1 * 3 + t2) * 3 + t3) * 3 + t4;
        #pragma unroll
        for (int c = 0; c < 40; ++c) acc[c] += wsh[c * 81 + tap] * xv;
    }

    ushort* ob = out + ((size_t)bx * 256 + tid) * 64;
    #pragma unroll
    for (int c = 0; c < 40; ++c){
        float v = acc[c] + bias[c]; v = v > 0.f ? v : 0.f;
        ob[c] = f2bf(v);
    }
    #pragma unroll
    for (int c = 40; c < 64; ++c) ob[c] = 0;
}

// ---------------- Layer 6: 40 real (stored 48) -> Cout=1, direct fp32 -------------------
__global__ __launch_bounds__(256) void conv_l6(
    const ushort* __restrict__ in, const float* __restrict__ w,
    const float* __restrict__ bias, float* __restrict__ out)
{
    __shared__ float wsh[3240];    // [ci=40][81]
    const int tid = threadIdx.x;
    const int bx = blockIdx.x;
    const int d2 = bx & 15, d1 = (bx >> 4) & 15, b = bx >> 8;
    for (int i = tid; i < 3240; i += 256) wsh[i] = w[i];
    __syncthreads();

    const int d3 = tid >> 4, d4 = tid & 15;
    const ushort* inb = in + (size_t)b * 65536 * 48;
    float acc = 0.f;
    for (int t1 = 0; t1 < 3; ++t1){
        int e1 = d1 + t1 - 1; if ((unsigned)e1 >= 16u) continue;
        for (int t2 = 0; t2 < 3; ++t2){
            int e2 = d2 + t2 - 1; if ((unsigned)e2 >= 16u) continue;
            for (int t3 = 0; t3 < 3; ++t3){
                int e3 = d3 + t3 - 1; if ((unsigned)e3 >= 16u) continue;
                for (int t4 = 0; t4 < 3; ++t4){
                    int e4 = d4 + t4 - 1; if ((unsigned)e4 >= 16u) continue;
                    const ushort* p = inb + (size_t)(((e1 * 16 + e2) * 16 + e3) * 16 + e4) * 48;
                    int tap = ((t1 * 3 + t2) * 3 + t3) * 3 + t4;
                    #pragma unroll
                    for (int c8 = 0; c8 < 5; ++c8){
                        short8 v = *(const short8*)(p + c8 * 8);
                        #pragma unroll
                        for (int j = 0; j < 8; ++j)
                            acc += bf2f((ushort)v[j]) * wsh[(c8 * 8 + j) * 81 + tap];
                    }
                }
            }
        }
    }
    float v = acc + bias[0]; v = v > 0.f ? v : 0.f;
    out[(size_t)bx * 256 + tid] = v;
}

// -------- Weight repack: [co][ci][81] fp32 -> wq[strip][chunk][1024 x 16B] bf16 ---------
// chunk = ((gg*KC + kh)*3 + t3); inside: linear unit u = [t4][gk][col] of the 3-tap
// B-chunk (no swizzle -- B is consumed straight from global/L2, no LDS banks involved).
__global__ void repack_wq(const float* __restrict__ w, ushort* __restrict__ wq,
                          int cin_real, int cout_real, int kc, int cout_w, int nstrip)
{
    const int ncc = 27 * kc;                  // 9 groups * kc * 3 t3
    const int total = nstrip * ncc * 8192;
    for (int o = blockIdx.x * blockDim.x + threadIdx.x; o < total; o += gridDim.x * blockDim.x){
        const int j = o & 7;
        const int u = (o >> 3) & 1023;
        const int chunk = o >> 13;
        const int strip = chunk / ncc;
        const int cc = chunk - strip * ncc;
        const int gg = cc / (kc * 3);
        const int rem = cc - gg * (kc * 3);
        const int kh = rem / 3;
        const int t3 = rem - kh * 3;
        float v = 0.f;
        if (u < 12 * cout_w){
            const int per = 4 * cout_w;
            const int t4 = u / per;
            const int rest = u - t4 * per;
            const int gk = rest / cout_w;
            const int col = rest - gk * cout_w;
            const int tap = gg * 9 + t3 * 3 + t4;
            const int ci = kh * 32 + gk * 8 + j;
            const int co = strip * cout_w + col;
            if (ci < cin_real && co < cout_real)
                v = w[((size_t)co * cin_real + ci) * 81 + tap];
        }
        wq[o] = f2bf(v);
    }
}

// ---------------- 16x16x32 MFMA implicit-GEMM conv layer --------------------------------
// in : [b][d1][d2][d3][d4][CIN_S]  bf16
// wq : chunk-contiguous weight layout (see repack_wq) -- read DIRECTLY from global (L2)
// out: [b][d1][d2][d3][d4][OST]    bf16; cols [CREAL,OST) zero-filled (PADC>0)
// Block: 256 thr = 4 waves; wave tile M64 x N=COUT_W (m4 x NT of 16x16x32).
// Only A lives in LDS: halo plane [18][18][32ch] per (group,kh) chunk, double-buffered,
// reg-staged (4 short8/thread). ONE barrier per chunk (3 t3-steps barrier-free):
//   chunk top: writeA(c+1) ds_writes (overlap compute) ... lgkmcnt(0); s_barrier.
// B fragments load per step straight from wq -- L2-resident, no LDS port, no staging.
template<int CIN_S, int COUT_W, int OST, int CREAL, int PADC>
__global__ __launch_bounds__(256, 3) void conv16(
    const ushort* __restrict__ in, const ushort* __restrict__ wq,
    const float* __restrict__ bias, ushort* __restrict__ out)
{
    constexpr int KC  = CIN_S / 32;            // A chunks per plane
    constexpr int NT  = COUT_W / 16;           // n-frags per wave
    constexpr int NCC = 27 * KC;               // B chunks per strip
    constexpr int AH  = 18 * 18 * 32;          // halo A chunk in shorts (10368)

    __shared__ __attribute__((aligned(16))) ushort As[2][AH];     // 2 x 20.25 KB

    const int tid  = threadIdx.x;
    const int lane = tid & 63;
    const int wm   = tid >> 6;                 // 0..3 (64-row M slice)
    const int r    = lane & 15;                // A-row offset / B-col / D-col
    const int g    = lane >> 4;                // k-group / D row-group

    // grid: [strips][512 plane blocks]; XCD-aware chunked swizzle on plane index
    const int p0 = blockIdx.x;
    const int strip = p0 >> 9;
    const int pp = p0 & 511;
    const int bx = (pp & 7) * 64 + (pp >> 3);
    const int d2 = bx & 15, d1 = (bx >> 4) & 15, b = bx >> 8;
    const int co_base = strip * COUT_W;

    const ushort* inb = in + (size_t)b * 65536 * CIN_S;
    const ushort* wqs = wq + ((size_t)strip * NCC << 13);

    // valid (t1,t2) groups packed 4 bits each
    unsigned long long gpack = 0ull; int ng = 0;
    #pragma unroll
    for (int gg = 0; gg < 9; ++gg){
        const int t1 = gg / 3, t2 = gg - (gg / 3) * 3;
        if ((unsigned)(d1 + t1 - 1) < 16u && (unsigned)(d2 + t2 - 1) < 16u){
            gpack |= ((unsigned long long)gg) << (ng * 4);
            ++ng;
        }
    }
    const int nchunk = ng * KC;

    f32x4 acc[4][NT];
    #pragma unroll
    for (int mi = 0; mi < 4; ++mi)
        #pragma unroll
        for (int n = 0; n < NT; ++n)
            acc[mi][n] = (f32x4){0.f, 0.f, 0.f, 0.f};

    short8 areg[4];
    const int e4s = lane >> 2;                 // 0..15
    const int jl  = lane & 3;
    const int gcs = jl ^ ((lane >> 3) & 3);    // pre-swizzled source ch-group

    auto loadAreg = [&](int c){
        const int gi = c / KC, kh = c - gi * KC;
        const int gg = (int)((gpack >> (gi * 4)) & 15ull);
        const int t1 = gg / 3, t2 = gg - t1 * 3;
        const ushort* src = inb + ((size_t)((d1 + t1 - 1) * 16 + (d2 + t2 - 1)) * 256) * CIN_S + kh * 32;
        #pragma unroll
        for (int k = 0; k < 4; ++k){
            const int row = wm * 4 + k;
            areg[k] = *(const short8*)(src + (size_t)(row * 16 + e4s) * CIN_S + gcs * 8);
        }
    };
    auto writeA = [&](ushort* dst){
        #pragma unroll
        for (int k = 0; k < 4; ++k){
            const int row = wm * 4 + k;
            *(short8*)(dst + ((row + 1) * 18 + 1 + e4s) * 32 + jl * 8) = areg[k];
        }
    };

    // prologue: zero BOTH halo buffers (halo cells stay zero forever), stage chunk 0.
    {
        const short8 z = {0, 0, 0, 0, 0, 0, 0, 0};
        short8* a0 = (short8*)As[0];
        short8* a1 = (short8*)As[1];
        for (int i = tid; i < AH / 8; i += 256){ a0[i] = z; a1[i] = z; }
    }
    asm volatile("s_waitcnt lgkmcnt(0)" ::: "memory");
    __builtin_amdgcn_s_barrier();
    loadAreg(0);
    writeA(As[0]);
    if (nchunk > 1) loadAreg(1);
    asm volatile("s_waitcnt lgkmcnt(0)" ::: "memory");
    __builtin_amdgcn_s_barrier();

    for (int c = 0; c < nchunk; ++c){
        // stage next A chunk (ds_writes overlap this chunk's compute; buffer's previous
        // readers -- chunk c-1 -- finished before the barrier that opened this chunk)
        if (c + 1 < nchunk) writeA(As[(c + 1) & 1]);

        const int gi = c / KC, kh = c - gi * KC;
        const int gg = (int)((gpack >> (gi * 4)) & 15ull);
        const ushort* Ab = As[c & 1];
        const ushort* Bg0 = wqs + ((size_t)((gg * KC + kh) * 3) << 13);

        #pragma unroll
        for (int t3 = 0; t3 < 3; ++t3){
            if (t3 == 1 && c + 2 < nchunk) loadAreg(c + 2);   // refill regs for next boundary
            const ushort* Bg = Bg0 + ((size_t)t3 << 13);
            __builtin_amdgcn_s_setprio(1);
            #pragma unroll
            for (int t4 = 0; t4 < 3; ++t4){
                const int e4 = r + t4 - 1;                    // -1..16, halo-safe
                const int gsw = (g ^ ((e4 >> 1) & 3)) * 8;
                const ushort* arow = Ab + ((wm * 4 + t3) * 18 + (e4 + 1)) * 32 + gsw;
                short8 bfr[NT];
                #pragma unroll
                for (int n = 0; n < NT; ++n)
                    bfr[n] = *(const short8*)(Bg + ((t4 * 4 + g) * COUT_W + n * 16 + r) * 8);
                #pragma unroll
                for (int mi = 0; mi < 4; ++mi){
                    const short8 af = *(const short8*)(arow + mi * (18 * 32));
                    #pragma unroll
                    for (int n = 0; n < NT; ++n)
                        acc[mi][n] = __builtin_amdgcn_mfma_f32_16x16x32_bf16(af, bfr[n], acc[mi][n], 0, 0, 0);
                }
            }
            __builtin_amdgcn_s_setprio(0);
        }

        // one barrier per chunk: A(c+1) ds_writes visible; readers of As[c&1] done
        // before chunk c+1's top overwrites the other buffer.
        asm volatile("s_waitcnt lgkmcnt(0)" ::: "memory");
        __builtin_amdgcn_s_barrier();
    }

    // epilogue: bias + ReLU + bf16 store. D frag: col = lane&15, row = g*4 + reg
    float bv[NT];
    #pragma unroll
    for (int n = 0; n < NT; ++n){
        const int co = co_base + n * 16 + r;
        bv[n] = (co < CREAL) ? bias[co] : 0.f;
    }
    ushort* ob = out + (size_t)bx * 256 * OST;
    #pragma unroll
    for (int mi = 0; mi < 4; ++mi){
        #pragma unroll
        for (int n = 0; n < NT; ++n){
            const int co = co_base + n * 16 + r;
            #pragma unroll
            for (int j = 0; j < 4; ++j){
                const int row = 64 * wm + 16 * mi + g * 4 + j;
                float v = acc[mi][n][j] + bv[n];
                v = v > 0.f ? v : 0.f;
                ob[(size_t)row * OST + co] = f2bf(v);
            }
        }
    }
    if (PADC > 0){
        const int row = 64 * wm + lane;
        const short8 z = {0, 0, 0, 0, 0, 0, 0, 0};
        #pragma unroll
        for (int pc = 0; pc < PADC; pc += 8)
            *(short8*)(ob + (size_t)row * OST + CREAL + pc) = z;
    }
}

extern "C" void kernel_launch(void* const* d_in, const int* in_sizes, int n_in,
                              void* d_out, int out_size, void* d_ws, size_t ws_size,
                              hipStream_t stream) {
    const float* x  = (const float*)d_in[0];
    const float* w1 = (const float*)d_in[1];  const float* b1 = (const float*)d_in[2];
    const float* w2 = (const float*)d_in[3];  const float* b2 = (const float*)d_in[4];
    const float* w3 = (const float*)d_in[5];  const float* b3 = (const float*)d_in[6];
    const float* w4 = (const float*)d_in[7];  const float* b4 = (const float*)d_in[8];
    const float* w5 = (const float*)d_in[9];  const float* b5 = (const float*)d_in[10];
    const float* w6 = (const float*)d_in[11]; const float* b6 = (const float*)d_in[12];

    // workspace layout (bf16 ushorts): activations + chunked weight packs
    ushort* bufA = (ushort*)d_ws;                       // [131072][160] : 41.9 MB
    ushort* bufB = bufA + (size_t)131072 * 160;         // [131072][96]  : 25.2 MB
    ushort* wq2  = bufB + (size_t)131072 * 96;          //  54 chunks * 8192
    ushort* wq3  = wq2 + (size_t)54  * 8192;            // 162 chunks * 8192 (2 strips)
    ushort* wq4  = wq3 + (size_t)162 * 8192;            // 135 chunks * 8192
    ushort* wq5  = wq4 + (size_t)135 * 8192;            //  81 chunks * 8192

    //                                      cin  cout  kc  cout_w  nstrip
    repack_wq<<<512, 256, 0, stream>>>(w2, wq2,  40,  80, 2, 80, 1);
    repack_wq<<<512, 256, 0, stream>>>(w3, wq3,  80, 160, 3, 80, 2);
    repack_wq<<<512, 256, 0, stream>>>(w4, wq4, 160,  80, 5, 80, 1);
    repack_wq<<<512, 256, 0, stream>>>(w5, wq5,  80,  40, 3, 48, 1);

    conv_l1<<<512, 256, 0, stream>>>(x, w1, b1, bufA);
    //       CIN_S  W   OST  CREAL PADC
    conv16<  64,   80,  96,  80,  16><<< 512, 256, 0, stream>>>(bufA, wq2, b2, bufB);
    conv16<  96,   80, 160, 160,   0><<<1024, 256, 0, stream>>>(bufB, wq3, b3, bufA);
    conv16< 160,   80,  96,  80,  16><<< 512, 256, 0, stream>>>(bufA, wq4, b4, bufB);
    conv16<  96,   48,  48,  40,   0><<< 512, 256, 0, stream>>>(bufB, wq5, b5, bufA);
    conv_l6<<<512, 256, 0, stream>>>(bufA, w6, b6, (float*)d_out);
}